// Round 1
// baseline (542.423 us; speedup 1.0000x reference)
//
#include <hip/hip_runtime.h>

#define HIDDEN 16

__global__ void k_init_deg(unsigned int* deg, int n) {
    int i = blockIdx.x * blockDim.x + threadIdx.x;
    if (i < n) deg[i] = 1u;  // self-loop
}

__global__ void k_count_deg(const int* __restrict__ dst, unsigned int* deg, int e) {
    int i = blockIdx.x * blockDim.x + threadIdx.x;
    if (i < e) atomicAdd(&deg[dst[i]], 1u);
}

__global__ void k_inv(const unsigned int* __restrict__ deg, float* __restrict__ inv, int n) {
    int i = blockIdx.x * blockDim.x + threadIdx.x;
    if (i < n) inv[i] = rsqrtf((float)deg[i]);  // deg >= 1 always (self-loop)
}

// one thread per (node, j): t1 = x@W1 ; acc1 init = b1 + self-loop term
__global__ void k_transform1(const float* __restrict__ x, const float* __restrict__ W1,
                             const float* __restrict__ b1, const float* __restrict__ inv,
                             float* __restrict__ t1, float* __restrict__ acc1, int n) {
    int tid = blockIdx.x * blockDim.x + threadIdx.x;
    if (tid >= n * HIDDEN) return;
    int i = tid >> 4, j = tid & 15;
    float x0 = x[3 * i], x1 = x[3 * i + 1], x2 = x[3 * i + 2];
    float t = x0 * W1[j] + x1 * W1[HIDDEN + j] + x2 * W1[2 * HIDDEN + j];
    t1[tid] = t;
    float iv = inv[i];
    acc1[tid] = b1[j] + t * iv * iv;  // self-loop norm = 1/deg
}

// one thread per (edge, j): coalesced gather + atomic scatter
__global__ void k_scatter1(const int* __restrict__ src, const int* __restrict__ dst,
                           const float* __restrict__ inv, const float* __restrict__ t1,
                           float* acc1, int e) {
    long long tid = (long long)blockIdx.x * blockDim.x + threadIdx.x;
    if (tid >= (long long)e * HIDDEN) return;
    int eid = (int)(tid >> 4), j = (int)(tid & 15);
    int s = src[eid], d = dst[eid];
    float c = inv[s] * inv[d];
    atomicAdd(&acc1[d * HIDDEN + j], c * t1[s * HIDDEN + j]);
}

// relu + dot with W2; out init = b2 + self-loop term
__global__ void k_transform2(const float* __restrict__ acc1, const float* __restrict__ W2,
                             const float* __restrict__ b2, const float* __restrict__ inv,
                             float* __restrict__ t2, float* __restrict__ out, int n) {
    int i = blockIdx.x * blockDim.x + threadIdx.x;
    if (i >= n) return;
    float t = 0.f;
#pragma unroll
    for (int j = 0; j < HIDDEN; j++) {
        float h = fmaxf(acc1[i * HIDDEN + j], 0.f);
        t += h * W2[j];
    }
    t2[i] = t;
    float iv = inv[i];
    out[i] = b2[0] + t * iv * iv;
}

__global__ void k_scatter2(const int* __restrict__ src, const int* __restrict__ dst,
                           const float* __restrict__ inv, const float* __restrict__ t2,
                           float* out, int e) {
    int i = blockIdx.x * blockDim.x + threadIdx.x;
    if (i >= e) return;
    int s = src[i], d = dst[i];
    atomicAdd(&out[d], inv[s] * inv[d] * t2[s]);
}

extern "C" void kernel_launch(void* const* d_in, const int* in_sizes, int n_in,
                              void* d_out, int out_size, void* d_ws, size_t ws_size,
                              hipStream_t stream) {
    const float* x  = (const float*)d_in[0];
    const int*   ei = (const int*)d_in[1];
    const float* W1 = (const float*)d_in[2];
    const float* b1 = (const float*)d_in[3];
    const float* W2 = (const float*)d_in[4];
    const float* b2 = (const float*)d_in[5];
    float* out = (float*)d_out;

    int n = in_sizes[0] / 3;
    int e = in_sizes[1] / 2;
    const int* src = ei;       // edge_index[0]
    const int* dst = ei + e;   // edge_index[1]

    // workspace layout (poisoned 0xAA each call -> every word we read is written first)
    unsigned int* deg = (unsigned int*)d_ws;          // n
    float* inv  = (float*)(deg + n);                  // n
    float* t1   = inv + n;                            // n*16
    float* acc1 = t1 + (size_t)n * HIDDEN;            // n*16
    float* t2   = acc1 + (size_t)n * HIDDEN;          // n

    const int B = 256;
    k_init_deg<<<(n + B - 1) / B, B, 0, stream>>>(deg, n);
    k_count_deg<<<(e + B - 1) / B, B, 0, stream>>>(dst, deg, e);
    k_inv<<<(n + B - 1) / B, B, 0, stream>>>(deg, inv, n);
    k_transform1<<<((long long)n * HIDDEN + B - 1) / B, B, 0, stream>>>(x, W1, b1, inv, t1, acc1, n);
    k_scatter1<<<((long long)e * HIDDEN + B - 1) / B, B, 0, stream>>>(src, dst, inv, t1, acc1, e);
    k_transform2<<<(n + B - 1) / B, B, 0, stream>>>(acc1, W2, b2, inv, t2, out, n);
    k_scatter2<<<(e + B - 1) / B, B, 0, stream>>>(src, dst, inv, t2, out, e);
}

// Round 2
// 515.347 us; speedup vs baseline: 1.0525x; 1.0525x over previous
//
#include <hip/hip_runtime.h>

#define HIDDEN 16
#define BN 64          // nodes per dst-bucket (power of two)
#define BN_SHIFT 6
#define NB_MAX 1600    // max buckets supported by LDS histograms (n <= 102400)
#define CHUNK 8192     // edges per block in hist/fill passes

// ======================= binned (LDS-accumulate) path =======================

__global__ void k_zero_cnt(unsigned int* cnt, int nb) {
    int i = blockIdx.x * blockDim.x + threadIdx.x;
    if (i < nb) cnt[i] = 0u;
}

__global__ void k_hist(const int* __restrict__ dst, int e, int nb,
                       unsigned int* __restrict__ cnt) {
    __shared__ unsigned int h[NB_MAX];
    for (int i = threadIdx.x; i < nb; i += blockDim.x) h[i] = 0u;
    __syncthreads();
    int start = blockIdx.x * CHUNK;
    int end = min(start + CHUNK, e);
    for (int i = start + threadIdx.x; i < end; i += blockDim.x)
        atomicAdd(&h[((unsigned)dst[i]) >> BN_SHIFT], 1u);
    __syncthreads();
    for (int i = threadIdx.x; i < nb; i += blockDim.x)
        if (h[i]) atomicAdd(&cnt[i], h[i]);
}

// single-block exclusive scan of cnt -> base, cursor
__global__ void k_scan(const unsigned int* __restrict__ cnt, int nb,
                       unsigned int* __restrict__ base,
                       unsigned int* __restrict__ cursor) {
    __shared__ unsigned int tsum[256];
    int t = threadIdx.x;
    int K = (nb + 255) / 256;
    unsigned int s = 0;
    for (int k = 0; k < K; k++) {
        int i = t * K + k;
        if (i < nb) s += cnt[i];
    }
    tsum[t] = s;
    __syncthreads();
    for (int off = 1; off < 256; off <<= 1) {
        unsigned int v = 0;
        if (t >= off) v = tsum[t - off];
        __syncthreads();
        if (t >= off) tsum[t] += v;
        __syncthreads();
    }
    unsigned int run = (t == 0) ? 0u : tsum[t - 1];
    for (int k = 0; k < K; k++) {
        int i = t * K + k;
        if (i < nb) { base[i] = run; cursor[i] = run; run += cnt[i]; }
    }
}

__global__ void k_fill(const int* __restrict__ src, const int* __restrict__ dst,
                       int e, int nb, unsigned int* cursor,
                       unsigned int* __restrict__ recs) {
    __shared__ unsigned int h[NB_MAX];
    __shared__ unsigned int lbase[NB_MAX];
    for (int i = threadIdx.x; i < nb; i += blockDim.x) h[i] = 0u;
    __syncthreads();
    int start = blockIdx.x * CHUNK;
    int end = min(start + CHUNK, e);
    for (int i = start + threadIdx.x; i < end; i += blockDim.x)
        atomicAdd(&h[((unsigned)dst[i]) >> BN_SHIFT], 1u);
    __syncthreads();
    for (int i = threadIdx.x; i < nb; i += blockDim.x) {
        unsigned int c = h[i];
        lbase[i] = c ? atomicAdd(&cursor[i], c) : 0u;
        h[i] = 0u;  // reuse as local rank cursor
    }
    __syncthreads();
    for (int i = start + threadIdx.x; i < end; i += blockDim.x) {
        unsigned int d = (unsigned)dst[i];
        unsigned int b = d >> BN_SHIFT;
        unsigned int r = atomicAdd(&h[b], 1u);
        recs[lbase[b] + r] = (((unsigned)src[i]) << BN_SHIFT) | (d & (BN - 1u));
    }
}

__global__ void k_deg_inv(const unsigned int* __restrict__ recs,
                          const unsigned int* __restrict__ base,
                          const unsigned int* __restrict__ cnt,
                          int n, float* __restrict__ inv) {
    __shared__ unsigned int degl[BN];
    if (threadIdx.x < BN) degl[threadIdx.x] = 1u;  // self-loop
    __syncthreads();
    int b = blockIdx.x;
    unsigned int s = base[b], m = cnt[b];
    for (unsigned int i = threadIdx.x; i < m; i += blockDim.x)
        atomicAdd(&degl[recs[s + i] & (BN - 1u)], 1u);
    __syncthreads();
    if (threadIdx.x < BN) {
        int node = b * BN + (int)threadIdx.x;
        if (node < n) inv[node] = rsqrtf((float)degl[threadIdx.x]);
    }
}

__global__ void k_transform1b(const float* __restrict__ x, const float* __restrict__ W1,
                              float* __restrict__ t1, int n) {
    int tid = blockIdx.x * blockDim.x + threadIdx.x;
    if (tid >= n * HIDDEN) return;
    int i = tid >> 4, j = tid & 15;
    t1[tid] = x[3 * i] * W1[j] + x[3 * i + 1] * W1[HIDDEN + j]
            + x[3 * i + 2] * W1[2 * HIDDEN + j];
}

// layer-1 scatter (LDS accumulate) + fused relu + layer-2 transform -> t2
__global__ void k_s1(const unsigned int* __restrict__ recs,
                     const unsigned int* __restrict__ base,
                     const unsigned int* __restrict__ cnt,
                     const float* __restrict__ inv, const float* __restrict__ t1,
                     const float* __restrict__ b1, const float* __restrict__ W2,
                     float* __restrict__ t2, int n) {
    __shared__ float acc[BN * HIDDEN];   // 4 KB
    __shared__ float invl[BN];
    for (int i = threadIdx.x; i < BN * HIDDEN; i += blockDim.x) acc[i] = 0.f;
    int b = blockIdx.x;
    if (threadIdx.x < BN) {
        int node = b * BN + (int)threadIdx.x;
        invl[threadIdx.x] = (node < n) ? inv[node] : 0.f;
    }
    __syncthreads();
    unsigned int s = base[b], m = cnt[b];
    int j = threadIdx.x & 15;
    int sub = threadIdx.x >> 4;  // 0..15 -> 16 edges in parallel
    for (unsigned int i = sub; i < m; i += 16) {
        unsigned int rec = recs[s + i];          // 16 lanes share one address
        unsigned int srcn = rec >> BN_SHIFT;
        unsigned int dl = rec & (BN - 1u);
        float v = t1[srcn * HIDDEN + j];         // coalesced 64B per edge
        float nm = inv[srcn] * invl[dl];
        atomicAdd(&acc[dl * HIDDEN + j], nm * v);
    }
    __syncthreads();
    if (threadIdx.x < BN) {
        int node = b * BN + (int)threadIdx.x;
        if (node < n) {
            float iv = invl[threadIdx.x];
            float selfc = iv * iv;  // self-loop norm = 1/deg
            float t = 0.f;
#pragma unroll
            for (int jj = 0; jj < HIDDEN; jj++) {
                float h = fmaxf(acc[threadIdx.x * HIDDEN + jj] + b1[jj]
                                + t1[node * HIDDEN + jj] * selfc, 0.f);
                t += h * W2[jj];
            }
            t2[node] = t;
        }
    }
}

// layer-2 scatter (LDS accumulate) + bias + self-loop -> out
__global__ void k_s2(const unsigned int* __restrict__ recs,
                     const unsigned int* __restrict__ base,
                     const unsigned int* __restrict__ cnt,
                     const float* __restrict__ inv, const float* __restrict__ t2,
                     const float* __restrict__ b2, float* __restrict__ out, int n) {
    __shared__ float o[BN];
    __shared__ float invl[BN];
    if (threadIdx.x < BN) {
        int node = blockIdx.x * BN + (int)threadIdx.x;
        o[threadIdx.x] = 0.f;
        invl[threadIdx.x] = (node < n) ? inv[node] : 0.f;
    }
    __syncthreads();
    unsigned int s = base[blockIdx.x], m = cnt[blockIdx.x];
    for (unsigned int i = threadIdx.x; i < m; i += blockDim.x) {
        unsigned int rec = recs[s + i];
        unsigned int srcn = rec >> BN_SHIFT;
        unsigned int dl = rec & (BN - 1u);
        atomicAdd(&o[dl], inv[srcn] * invl[dl] * t2[srcn]);
    }
    __syncthreads();
    if (threadIdx.x < BN) {
        int node = blockIdx.x * BN + (int)threadIdx.x;
        if (node < n)
            out[node] = b2[0] + o[threadIdx.x]
                      + t2[node] * invl[threadIdx.x] * invl[threadIdx.x];
    }
}

// ======================= fallback (global-atomic) path =======================

__global__ void k_init_deg(unsigned int* deg, int n) {
    int i = blockIdx.x * blockDim.x + threadIdx.x;
    if (i < n) deg[i] = 1u;
}
__global__ void k_count_deg(const int* __restrict__ dst, unsigned int* deg, int e) {
    int i = blockIdx.x * blockDim.x + threadIdx.x;
    if (i < e) atomicAdd(&deg[dst[i]], 1u);
}
__global__ void k_inv(const unsigned int* __restrict__ deg, float* __restrict__ inv, int n) {
    int i = blockIdx.x * blockDim.x + threadIdx.x;
    if (i < n) inv[i] = rsqrtf((float)deg[i]);
}
__global__ void k_transform1(const float* __restrict__ x, const float* __restrict__ W1,
                             const float* __restrict__ b1, const float* __restrict__ inv,
                             float* __restrict__ t1, float* __restrict__ acc1, int n) {
    int tid = blockIdx.x * blockDim.x + threadIdx.x;
    if (tid >= n * HIDDEN) return;
    int i = tid >> 4, j = tid & 15;
    float t = x[3 * i] * W1[j] + x[3 * i + 1] * W1[HIDDEN + j] + x[3 * i + 2] * W1[2 * HIDDEN + j];
    t1[tid] = t;
    float iv = inv[i];
    acc1[tid] = b1[j] + t * iv * iv;
}
__global__ void k_scatter1(const int* __restrict__ src, const int* __restrict__ dst,
                           const float* __restrict__ inv, const float* __restrict__ t1,
                           float* acc1, int e) {
    long long tid = (long long)blockIdx.x * blockDim.x + threadIdx.x;
    if (tid >= (long long)e * HIDDEN) return;
    int eid = (int)(tid >> 4), j = (int)(tid & 15);
    int s = src[eid], d = dst[eid];
    atomicAdd(&acc1[d * HIDDEN + j], inv[s] * inv[d] * t1[s * HIDDEN + j]);
}
__global__ void k_transform2(const float* __restrict__ acc1, const float* __restrict__ W2,
                             const float* __restrict__ b2, const float* __restrict__ inv,
                             float* __restrict__ t2, float* __restrict__ out, int n) {
    int i = blockIdx.x * blockDim.x + threadIdx.x;
    if (i >= n) return;
    float t = 0.f;
#pragma unroll
    for (int j = 0; j < HIDDEN; j++) t += fmaxf(acc1[i * HIDDEN + j], 0.f) * W2[j];
    t2[i] = t;
    float iv = inv[i];
    out[i] = b2[0] + t * iv * iv;
}
__global__ void k_scatter2(const int* __restrict__ src, const int* __restrict__ dst,
                           const float* __restrict__ inv, const float* __restrict__ t2,
                           float* out, int e) {
    int i = blockIdx.x * blockDim.x + threadIdx.x;
    if (i >= e) return;
    int s = src[i], d = dst[i];
    atomicAdd(&out[d], inv[s] * inv[d] * t2[s]);
}

// ======================= launch =======================

extern "C" void kernel_launch(void* const* d_in, const int* in_sizes, int n_in,
                              void* d_out, int out_size, void* d_ws, size_t ws_size,
                              hipStream_t stream) {
    const float* x  = (const float*)d_in[0];
    const int*   ei = (const int*)d_in[1];
    const float* W1 = (const float*)d_in[2];
    const float* b1 = (const float*)d_in[3];
    const float* W2 = (const float*)d_in[4];
    const float* b2 = (const float*)d_in[5];
    float* out = (float*)d_out;

    int n = in_sizes[0] / 3;
    int e = in_sizes[1] / 2;
    const int* src = ei;
    const int* dst = ei + e;
    const int B = 256;

    int nb = (n + BN - 1) / BN;
    size_t need = (size_t)nb * 4 * 3 + (size_t)e * 4 + (size_t)n * 4
                + (size_t)n * HIDDEN * 4 + (size_t)n * 4;
    bool use_binned = (nb <= NB_MAX) && (ws_size >= need);

    if (use_binned) {
        unsigned int* cnt    = (unsigned int*)d_ws;           // nb
        unsigned int* basep  = cnt + nb;                      // nb
        unsigned int* cursor = basep + nb;                    // nb
        unsigned int* recs   = cursor + nb;                   // e
        float* inv = (float*)(recs + e);                      // n
        float* t1  = inv + n;                                 // n*16
        float* t2  = t1 + (size_t)n * HIDDEN;                 // n

        int gridE = (e + CHUNK - 1) / CHUNK;
        k_zero_cnt<<<(nb + B - 1) / B, B, 0, stream>>>(cnt, nb);
        k_hist<<<gridE, B, 0, stream>>>(dst, e, nb, cnt);
        k_scan<<<1, B, 0, stream>>>(cnt, nb, basep, cursor);
        k_fill<<<gridE, B, 0, stream>>>(src, dst, e, nb, cursor, recs);
        k_transform1b<<<((long long)n * HIDDEN + B - 1) / B, B, 0, stream>>>(x, W1, t1, n);
        k_deg_inv<<<nb, B, 0, stream>>>(recs, basep, cnt, n, inv);
        k_s1<<<nb, B, 0, stream>>>(recs, basep, cnt, inv, t1, b1, W2, t2, n);
        k_s2<<<nb, B, 0, stream>>>(recs, basep, cnt, inv, t2, b2, out, n);
    } else {
        unsigned int* deg = (unsigned int*)d_ws;
        float* inv  = (float*)(deg + n);
        float* t1   = inv + n;
        float* acc1 = t1 + (size_t)n * HIDDEN;
        float* t2   = acc1 + (size_t)n * HIDDEN;

        k_init_deg<<<(n + B - 1) / B, B, 0, stream>>>(deg, n);
        k_count_deg<<<(e + B - 1) / B, B, 0, stream>>>(dst, deg, e);
        k_inv<<<(n + B - 1) / B, B, 0, stream>>>(deg, inv, n);
        k_transform1<<<((long long)n * HIDDEN + B - 1) / B, B, 0, stream>>>(x, W1, b1, inv, t1, acc1, n);
        k_scatter1<<<((long long)e * HIDDEN + B - 1) / B, B, 0, stream>>>(src, dst, inv, t1, acc1, e);
        k_transform2<<<(n + B - 1) / B, B, 0, stream>>>(acc1, W2, b2, inv, t2, out, n);
        k_scatter2<<<(e + B - 1) / B, B, 0, stream>>>(src, dst, inv, t2, out, e);
    }
}

// Round 3
// 255.126 us; speedup vs baseline: 2.1261x; 2.0200x over previous
//
#include <hip/hip_runtime.h>

#define HIDDEN 16
#define BN 64          // nodes per dst-bucket (power of two)
#define BN_SHIFT 6
#define NB_MAX 1600    // max buckets supported by LDS histograms (n <= 102400)
#define CHUNK 8192     // edges per block in hist/fill passes

// ======================= binned (LDS-accumulate) path =======================

__global__ void k_zero_cnt(unsigned int* cnt, int nb) {
    int i = blockIdx.x * blockDim.x + threadIdx.x;
    if (i < nb) cnt[i] = 0u;
}

__global__ void k_hist(const int* __restrict__ dst, int e, int nb,
                       unsigned int* __restrict__ cnt) {
    __shared__ unsigned int h[NB_MAX];
    for (int i = threadIdx.x; i < nb; i += blockDim.x) h[i] = 0u;
    __syncthreads();
    int start = blockIdx.x * CHUNK;
    int end = min(start + CHUNK, e);
    for (int i = start + threadIdx.x; i < end; i += blockDim.x)
        atomicAdd(&h[((unsigned)dst[i]) >> BN_SHIFT], 1u);
    __syncthreads();
    for (int i = threadIdx.x; i < nb; i += blockDim.x)
        if (h[i]) atomicAdd(&cnt[i], h[i]);
}

// single-block exclusive scan of cnt -> base, cursor
__global__ void k_scan(const unsigned int* __restrict__ cnt, int nb,
                       unsigned int* __restrict__ base,
                       unsigned int* __restrict__ cursor) {
    __shared__ unsigned int tsum[256];
    int t = threadIdx.x;
    int K = (nb + 255) / 256;
    unsigned int s = 0;
    for (int k = 0; k < K; k++) {
        int i = t * K + k;
        if (i < nb) s += cnt[i];
    }
    tsum[t] = s;
    __syncthreads();
    for (int off = 1; off < 256; off <<= 1) {
        unsigned int v = 0;
        if (t >= off) v = tsum[t - off];
        __syncthreads();
        if (t >= off) tsum[t] += v;
        __syncthreads();
    }
    unsigned int run = (t == 0) ? 0u : tsum[t - 1];
    for (int k = 0; k < K; k++) {
        int i = t * K + k;
        if (i < nb) { base[i] = run; cursor[i] = run; run += cnt[i]; }
    }
}

__global__ void k_fill(const int* __restrict__ src, const int* __restrict__ dst,
                       int e, int nb, unsigned int* cursor,
                       unsigned int* __restrict__ recs) {
    __shared__ unsigned int h[NB_MAX];
    __shared__ unsigned int lbase[NB_MAX];
    for (int i = threadIdx.x; i < nb; i += blockDim.x) h[i] = 0u;
    __syncthreads();
    int start = blockIdx.x * CHUNK;
    int end = min(start + CHUNK, e);
    for (int i = start + threadIdx.x; i < end; i += blockDim.x)
        atomicAdd(&h[((unsigned)dst[i]) >> BN_SHIFT], 1u);
    __syncthreads();
    for (int i = threadIdx.x; i < nb; i += blockDim.x) {
        unsigned int c = h[i];
        lbase[i] = c ? atomicAdd(&cursor[i], c) : 0u;
        h[i] = 0u;  // reuse as local rank cursor
    }
    __syncthreads();
    for (int i = start + threadIdx.x; i < end; i += blockDim.x) {
        unsigned int d = (unsigned)dst[i];
        unsigned int b = d >> BN_SHIFT;
        unsigned int r = atomicAdd(&h[b], 1u);
        recs[lbase[b] + r] = (((unsigned)src[i]) << BN_SHIFT) | (d & (BN - 1u));
    }
}

__global__ void k_deg_inv(const unsigned int* __restrict__ recs,
                          const unsigned int* __restrict__ base,
                          const unsigned int* __restrict__ cnt,
                          int n, float* __restrict__ inv) {
    __shared__ unsigned int degl[BN];
    if (threadIdx.x < BN) degl[threadIdx.x] = 1u;  // self-loop
    __syncthreads();
    int b = blockIdx.x;
    unsigned int s = base[b], m = cnt[b];
    for (unsigned int i = threadIdx.x; i < m; i += blockDim.x)
        atomicAdd(&degl[recs[s + i] & (BN - 1u)], 1u);
    __syncthreads();
    if (threadIdx.x < BN) {
        int node = b * BN + (int)threadIdx.x;
        if (node < n) inv[node] = rsqrtf((float)degl[threadIdx.x]);
    }
}

// layer-1 aggregate of RAW x (3 feats, 1.2 MB table -> L2-resident gather),
// then per-node W1 + b1 + relu + W2 epilogue -> t2.
// segment_sum(norm*(x@W1)[src]) == segment_sum(norm*x[src]) @ W1  (linearity)
__global__ void k_s1x(const unsigned int* __restrict__ recs,
                      const unsigned int* __restrict__ base,
                      const unsigned int* __restrict__ cnt,
                      const float* __restrict__ inv, const float* __restrict__ x,
                      const float* __restrict__ W1, const float* __restrict__ b1,
                      const float* __restrict__ W2,
                      float* __restrict__ t2, int n) {
    // k-major accumulators: bank = dl%32 -> free 2-way aliasing only
    __shared__ float a0[BN], a1[BN], a2[BN];
    __shared__ float invl[BN];
    int t = threadIdx.x;
    if (t < BN) {
        int node = blockIdx.x * BN + t;
        a0[t] = 0.f; a1[t] = 0.f; a2[t] = 0.f;
        invl[t] = (node < n) ? inv[node] : 0.f;
    }
    __syncthreads();
    unsigned int s = base[blockIdx.x], m = cnt[blockIdx.x];
    for (unsigned int i = t; i < m; i += blockDim.x) {
        unsigned int rec = recs[s + i];           // coalesced
        unsigned int srcn = rec >> BN_SHIFT;
        unsigned int dl = rec & (BN - 1u);
        float nm = inv[srcn] * invl[dl];          // inv: 400 KB, L2-hit
        float x0 = x[srcn * 3];                   // x: 1.2 MB, L2-hit
        float x1 = x[srcn * 3 + 1];
        float x2 = x[srcn * 3 + 2];
        atomicAdd(&a0[dl], nm * x0);
        atomicAdd(&a1[dl], nm * x1);
        atomicAdd(&a2[dl], nm * x2);
    }
    __syncthreads();
    if (t < BN) {
        int node = blockIdx.x * BN + t;
        if (node < n) {
            float iv = invl[t];
            float selfc = iv * iv;                // self-loop norm = 1/deg
            float v0 = a0[t] + x[node * 3] * selfc;
            float v1 = a1[t] + x[node * 3 + 1] * selfc;
            float v2 = a2[t] + x[node * 3 + 2] * selfc;
            float acc = 0.f;
#pragma unroll
            for (int j = 0; j < HIDDEN; j++) {
                float h = fmaxf(v0 * W1[j] + v1 * W1[HIDDEN + j]
                                + v2 * W1[2 * HIDDEN + j] + b1[j], 0.f);
                acc += h * W2[j];
            }
            t2[node] = acc;
        }
    }
}

// layer-2 scatter (LDS accumulate) + bias + self-loop -> out
__global__ void k_s2(const unsigned int* __restrict__ recs,
                     const unsigned int* __restrict__ base,
                     const unsigned int* __restrict__ cnt,
                     const float* __restrict__ inv, const float* __restrict__ t2,
                     const float* __restrict__ b2, float* __restrict__ out, int n) {
    __shared__ float o[BN];
    __shared__ float invl[BN];
    if (threadIdx.x < BN) {
        int node = blockIdx.x * BN + (int)threadIdx.x;
        o[threadIdx.x] = 0.f;
        invl[threadIdx.x] = (node < n) ? inv[node] : 0.f;
    }
    __syncthreads();
    unsigned int s = base[blockIdx.x], m = cnt[blockIdx.x];
    for (unsigned int i = threadIdx.x; i < m; i += blockDim.x) {
        unsigned int rec = recs[s + i];
        unsigned int srcn = rec >> BN_SHIFT;
        unsigned int dl = rec & (BN - 1u);
        atomicAdd(&o[dl], inv[srcn] * invl[dl] * t2[srcn]);  // t2: 400 KB, L2-hit
    }
    __syncthreads();
    if (threadIdx.x < BN) {
        int node = blockIdx.x * BN + (int)threadIdx.x;
        if (node < n)
            out[node] = b2[0] + o[threadIdx.x]
                      + t2[node] * invl[threadIdx.x] * invl[threadIdx.x];
    }
}

// ======================= fallback (global-atomic) path =======================

__global__ void k_init_deg(unsigned int* deg, int n) {
    int i = blockIdx.x * blockDim.x + threadIdx.x;
    if (i < n) deg[i] = 1u;
}
__global__ void k_count_deg(const int* __restrict__ dst, unsigned int* deg, int e) {
    int i = blockIdx.x * blockDim.x + threadIdx.x;
    if (i < e) atomicAdd(&deg[dst[i]], 1u);
}
__global__ void k_inv(const unsigned int* __restrict__ deg, float* __restrict__ inv, int n) {
    int i = blockIdx.x * blockDim.x + threadIdx.x;
    if (i < n) inv[i] = rsqrtf((float)deg[i]);
}
__global__ void k_transform1(const float* __restrict__ x, const float* __restrict__ W1,
                             const float* __restrict__ b1, const float* __restrict__ inv,
                             float* __restrict__ t1, float* __restrict__ acc1, int n) {
    int tid = blockIdx.x * blockDim.x + threadIdx.x;
    if (tid >= n * HIDDEN) return;
    int i = tid >> 4, j = tid & 15;
    float t = x[3 * i] * W1[j] + x[3 * i + 1] * W1[HIDDEN + j] + x[3 * i + 2] * W1[2 * HIDDEN + j];
    t1[tid] = t;
    float iv = inv[i];
    acc1[tid] = b1[j] + t * iv * iv;
}
__global__ void k_scatter1(const int* __restrict__ src, const int* __restrict__ dst,
                           const float* __restrict__ inv, const float* __restrict__ t1,
                           float* acc1, int e) {
    long long tid = (long long)blockIdx.x * blockDim.x + threadIdx.x;
    if (tid >= (long long)e * HIDDEN) return;
    int eid = (int)(tid >> 4), j = (int)(tid & 15);
    int s = src[eid], d = dst[eid];
    atomicAdd(&acc1[d * HIDDEN + j], inv[s] * inv[d] * t1[s * HIDDEN + j]);
}
__global__ void k_transform2(const float* __restrict__ acc1, const float* __restrict__ W2,
                             const float* __restrict__ b2, const float* __restrict__ inv,
                             float* __restrict__ t2, float* __restrict__ out, int n) {
    int i = blockIdx.x * blockDim.x + threadIdx.x;
    if (i >= n) return;
    float t = 0.f;
#pragma unroll
    for (int j = 0; j < HIDDEN; j++) t += fmaxf(acc1[i * HIDDEN + j], 0.f) * W2[j];
    t2[i] = t;
    float iv = inv[i];
    out[i] = b2[0] + t * iv * iv;
}
__global__ void k_scatter2(const int* __restrict__ src, const int* __restrict__ dst,
                           const float* __restrict__ inv, const float* __restrict__ t2,
                           float* out, int e) {
    int i = blockIdx.x * blockDim.x + threadIdx.x;
    if (i >= e) return;
    int s = src[i], d = dst[i];
    atomicAdd(&out[d], inv[s] * inv[d] * t2[s]);
}

// ======================= launch =======================

extern "C" void kernel_launch(void* const* d_in, const int* in_sizes, int n_in,
                              void* d_out, int out_size, void* d_ws, size_t ws_size,
                              hipStream_t stream) {
    const float* x  = (const float*)d_in[0];
    const int*   ei = (const int*)d_in[1];
    const float* W1 = (const float*)d_in[2];
    const float* b1 = (const float*)d_in[3];
    const float* W2 = (const float*)d_in[4];
    const float* b2 = (const float*)d_in[5];
    float* out = (float*)d_out;

    int n = in_sizes[0] / 3;
    int e = in_sizes[1] / 2;
    const int* src = ei;
    const int* dst = ei + e;
    const int B = 256;

    int nb = (n + BN - 1) / BN;
    size_t need = (size_t)nb * 4 * 3 + (size_t)e * 4 + (size_t)n * 8;
    bool use_binned = (nb <= NB_MAX) && (ws_size >= need);

    if (use_binned) {
        unsigned int* cnt    = (unsigned int*)d_ws;           // nb
        unsigned int* basep  = cnt + nb;                      // nb
        unsigned int* cursor = basep + nb;                    // nb
        unsigned int* recs   = cursor + nb;                   // e
        float* inv = (float*)(recs + e);                      // n
        float* t2  = inv + n;                                 // n

        int gridE = (e + CHUNK - 1) / CHUNK;
        k_zero_cnt<<<(nb + B - 1) / B, B, 0, stream>>>(cnt, nb);
        k_hist<<<gridE, B, 0, stream>>>(dst, e, nb, cnt);
        k_scan<<<1, B, 0, stream>>>(cnt, nb, basep, cursor);
        k_fill<<<gridE, B, 0, stream>>>(src, dst, e, nb, cursor, recs);
        k_deg_inv<<<nb, B, 0, stream>>>(recs, basep, cnt, n, inv);
        k_s1x<<<nb, B, 0, stream>>>(recs, basep, cnt, inv, x, W1, b1, W2, t2, n);
        k_s2<<<nb, B, 0, stream>>>(recs, basep, cnt, inv, t2, b2, out, n);
    } else {
        unsigned int* deg = (unsigned int*)d_ws;
        float* inv  = (float*)(deg + n);
        float* t1   = inv + n;
        float* acc1 = t1 + (size_t)n * HIDDEN;
        float* t2   = acc1 + (size_t)n * HIDDEN;

        k_init_deg<<<(n + B - 1) / B, B, 0, stream>>>(deg, n);
        k_count_deg<<<(e + B - 1) / B, B, 0, stream>>>(dst, deg, e);
        k_inv<<<(n + B - 1) / B, B, 0, stream>>>(deg, inv, n);
        k_transform1<<<((long long)n * HIDDEN + B - 1) / B, B, 0, stream>>>(x, W1, b1, inv, t1, acc1, n);
        k_scatter1<<<((long long)e * HIDDEN + B - 1) / B, B, 0, stream>>>(src, dst, inv, t1, acc1, e);
        k_transform2<<<(n + B - 1) / B, B, 0, stream>>>(acc1, W2, b2, inv, t2, out, n);
        k_scatter2<<<(e + B - 1) / B, B, 0, stream>>>(src, dst, inv, t2, out, e);
    }
}